// Round 4
// baseline (847.008 us; speedup 1.0000x reference)
//
#include <hip/hip_runtime.h>

#define D256 256
#define ALEN 128
#define INDIM 512
#define BSZ 32
#define TLEN 2048
#define CHL 32     // chunk length
#define NCH 64     // number of chunks

typedef __attribute__((ext_vector_type(8))) short short8;  // 8 x bf16
typedef __attribute__((ext_vector_type(4))) float f32x4;
typedef __attribute__((ext_vector_type(8))) unsigned short u16x8;

__device__ __forceinline__ float leakyf(float x)  { return x < 0.f ? 0.01f * x : x; }
__device__ __forceinline__ float ileakyf(float x) { return x < 0.f ? x * 100.0f : x; }

__device__ __forceinline__ unsigned short f2bf(float f) {
  unsigned int x = __float_as_uint(f);
  unsigned int r = x + 0x7FFFu + ((x >> 16) & 1u);  // RNE
  return (unsigned short)(r >> 16);
}

__device__ __forceinline__ float bf2f(unsigned short u) {
  return __uint_as_float(((unsigned int)u) << 16);
}

__device__ __forceinline__ void gload16(const void* g, const void* l) {
  __builtin_amdgcn_global_load_lds(
      (const __attribute__((address_space(1))) unsigned int*)g,
      (__attribute__((address_space(3))) unsigned int*)l, 16, 0, 0);
}

// cross-lane adds for the 8-way d-group reduction (dg = lane & 7).
template <int CTRL>
__device__ __forceinline__ float dpp_addf(float x) {
  return x + __int_as_float(__builtin_amdgcn_update_dpp(
                 0, __float_as_int(x), CTRL, 0xF, 0xF, true));
}
__device__ __forceinline__ void red8(float4& s) {
  s.x = dpp_addf<0xB1>(s.x); s.y = dpp_addf<0xB1>(s.y);
  s.z = dpp_addf<0xB1>(s.z); s.w = dpp_addf<0xB1>(s.w);   // xor 1
  s.x = dpp_addf<0x4E>(s.x); s.y = dpp_addf<0x4E>(s.y);
  s.z = dpp_addf<0x4E>(s.z); s.w = dpp_addf<0x4E>(s.w);   // xor 2
  s.x = dpp_addf<0x141>(s.x); s.y = dpp_addf<0x141>(s.y);
  s.z = dpp_addf<0x141>(s.z); s.w = dpp_addf<0x141>(s.w); // half-mirror (xor4-equiv)
}

// ---------------------------------------------------------------------------
// bf16 MFMA GEMM (m97 structure): Out[m][n] = sum_k In[m][k]*W[n][k]
// (+bias1[n]+bias2[n], optional inv_leaky). 128x128 tile, BK=32, 4 waves.
// Epilogue: LDS-bounced in 4 passes of 32 rows -> 16B coalesced stores
// (old path: 64 scalar 2-4B scattered stores/thread).
// ---------------------------------------------------------------------------
__global__ __launch_bounds__(256) void gemm_mfma(
    const unsigned short* __restrict__ In, int K,
    const unsigned short* __restrict__ W,
    const float* __restrict__ bias1, const float* __restrict__ bias2,
    int ileaky_act, int out_bf16, void* __restrict__ Outp) {
  __shared__ char lds[16384];
  __shared__ float ldsF[32][132];
  const int tid = threadIdx.x;
  const int lane = tid & 63, w = tid >> 6;
  const int m0 = blockIdx.x * 128, n0 = blockIdx.y * 128;
  const int wm = (w & 1) * 64, wn = (w >> 1) * 64;
  const int quad = lane >> 4, l16 = lane & 15;

  f32x4 acc[4][4];
#pragma unroll
  for (int i = 0; i < 4; ++i)
#pragma unroll
    for (int j = 0; j < 4; ++j) acc[i][j] = {0.f, 0.f, 0.f, 0.f};

  for (int kb = 0; kb < K; kb += 32) {
    __syncthreads();
#pragma unroll
    for (int q = 0; q < 2; ++q) {
      const int id = (w * 2 + q) * 64 + lane;
      const int row = id >> 2, ch = id & 3;
      gload16(In + (size_t)(m0 + row) * K + kb + ch * 8,
              lds + (w * 2 + q) * 1024);
      gload16(W + (size_t)(n0 + row) * K + kb + ch * 8,
              lds + 8192 + (w * 2 + q) * 1024);
    }
    __syncthreads();

    short8 af[4], bf[4];
#pragma unroll
    for (int i = 0; i < 4; ++i) {
      af[i] = *(const short8*)(lds + ((wm + i * 16 + l16) * 64 + quad * 16));
      bf[i] = *(const short8*)(lds + 8192 + ((wn + i * 16 + l16) * 64 + quad * 16));
    }
#pragma unroll
    for (int i = 0; i < 4; ++i)
#pragma unroll
      for (int j = 0; j < 4; ++j)
        acc[i][j] = __builtin_amdgcn_mfma_f32_16x16x32_bf16(af[i], bf[j], acc[i][j], 0, 0, 0);
  }

  // -------- coalesced epilogue: 4 passes of 32 rows through ldsF --------
  const int lrow = tid >> 3, c0 = (tid & 7) * 16;
#pragma unroll
  for (int p = 0; p < 4; ++p) {
    if ((w & 1) == (p >> 1)) {
      const int ib = 2 * (p & 1);
#pragma unroll
      for (int ii = 0; ii < 2; ++ii)
#pragma unroll
        for (int j = 0; j < 4; ++j)
#pragma unroll
          for (int r = 0; r < 4; ++r)
            ldsF[ii * 16 + quad * 4 + r][wn + j * 16 + l16] = acc[ib + ii][j][r];
    }
    __syncthreads();
    const int m = m0 + p * 32 + lrow;
    const int nb = n0 + c0;
    float v[16];
#pragma unroll
    for (int k = 0; k < 4; ++k) {
      const float4 b1 = *(const float4*)&bias1[nb + 4 * k];
#pragma unroll
      for (int c = 0; c < 4; ++c) v[4 * k + c] = ldsF[lrow][c0 + 4 * k + c] + ((const float*)&b1)[c];
    }
    if (bias2) {
#pragma unroll
      for (int k = 0; k < 4; ++k) {
        const float4 b2 = *(const float4*)&bias2[nb + 4 * k];
#pragma unroll
        for (int c = 0; c < 4; ++c) v[4 * k + c] += ((const float*)&b2)[c];
      }
    }
    if (ileaky_act) {
#pragma unroll
      for (int c = 0; c < 16; ++c) v[c] = ileakyf(v[c]);
    }
    if (out_bf16) {
      unsigned short* op = (unsigned short*)Outp + (size_t)m * 256 + nb;
#pragma unroll
      for (int h = 0; h < 2; ++h) {
        u16x8 ov;
#pragma unroll
        for (int c = 0; c < 8; ++c) ov[c] = f2bf(v[h * 8 + c]);
        *(u16x8*)(op + h * 8) = ov;
      }
    } else {
      float* op = (float*)Outp + (size_t)m * 256 + nb;
#pragma unroll
      for (int k = 0; k < 4; ++k)
        *(float4*)(op + 4 * k) = make_float4(v[4 * k], v[4 * k + 1], v[4 * k + 2], v[4 * k + 3]);
    }
    __syncthreads();
  }
}

// ---------------------------------------------------------------------------
// Correction GEMM: w1[b, k*CHL+jj, e] = bf16(ileaky( sum_d E[(k,b),d]*A^{jj+1}[e,d]
//   + d[b, k*CHL+jj, e] )).  In = Eb [2048][256] bf16; W = Mstackb [8192][256]
//   bf16 (row n = jj*256+e holds A^{jj+1}[e][:]); d = bf16, stored by
//   phase_kernel in the SAME buffer w1 (read-then-overwrite per element by
//   the owning thread). Coalesced LDS-bounced epilogue.
// ---------------------------------------------------------------------------
__global__ __launch_bounds__(256) void gemm_corr(
    const unsigned short* __restrict__ Eb, const unsigned short* __restrict__ Mb,
    unsigned short* w1 /* aliased: d in, w1 out */) {
  __shared__ char lds[16384];
  __shared__ float ldsF[32][132];
  const int tid = threadIdx.x;
  const int lane = tid & 63, w = tid >> 6;
  const int m0 = blockIdx.x * 128, n0 = blockIdx.y * 128;
  const int wm = (w & 1) * 64, wn = (w >> 1) * 64;
  const int quad = lane >> 4, l16 = lane & 15;

  f32x4 acc[4][4];
#pragma unroll
  for (int i = 0; i < 4; ++i)
#pragma unroll
    for (int j = 0; j < 4; ++j) acc[i][j] = {0.f, 0.f, 0.f, 0.f};

  for (int kb = 0; kb < 256; kb += 32) {
    __syncthreads();
#pragma unroll
    for (int q = 0; q < 2; ++q) {
      const int id = (w * 2 + q) * 64 + lane;
      const int row = id >> 2, ch = id & 3;
      gload16(Eb + (size_t)(m0 + row) * 256 + kb + ch * 8,
              lds + (w * 2 + q) * 1024);
      gload16(Mb + (size_t)(n0 + row) * 256 + kb + ch * 8,
              lds + 8192 + (w * 2 + q) * 1024);
    }
    __syncthreads();

    short8 af[4], bf[4];
#pragma unroll
    for (int i = 0; i < 4; ++i) {
      af[i] = *(const short8*)(lds + ((wm + i * 16 + l16) * 64 + quad * 16));
      bf[i] = *(const short8*)(lds + 8192 + ((wn + i * 16 + l16) * 64 + quad * 16));
    }
#pragma unroll
    for (int i = 0; i < 4; ++i)
#pragma unroll
      for (int j = 0; j < 4; ++j)
        acc[i][j] = __builtin_amdgcn_mfma_f32_16x16x32_bf16(af[i], bf[j], acc[i][j], 0, 0, 0);
  }

  // -------- coalesced epilogue; d-read + w1-write at identical addrs -----
  const int lrow = tid >> 3, c0 = (tid & 7) * 16;
#pragma unroll
  for (int p = 0; p < 4; ++p) {
    if ((w & 1) == (p >> 1)) {
      const int ib = 2 * (p & 1);
#pragma unroll
      for (int ii = 0; ii < 2; ++ii)
#pragma unroll
        for (int j = 0; j < 4; ++j)
#pragma unroll
          for (int r = 0; r < 4; ++r)
            ldsF[ii * 16 + quad * 4 + r][wn + j * 16 + l16] = acc[ib + ii][j][r];
    }
    __syncthreads();
    const int m = m0 + p * 32 + lrow;
    const int kk = m >> 5, bb = m & 31;
    const int nb = n0 + c0;
    const int jj = nb >> 8, e = nb & 255;
    const size_t addr = ((size_t)bb * TLEN + (size_t)kk * CHL + jj) * 256 + e;
#pragma unroll
    for (int h = 0; h < 2; ++h) {
      const u16x8 dv = *(const u16x8*)&w1[addr + h * 8];
      u16x8 ov;
#pragma unroll
      for (int c = 0; c < 8; ++c) {
        float v = ldsF[lrow][c0 + h * 8 + c] + bf2f(dv[c]);
        ov[c] = f2bf(ileakyf(v));
      }
      *(u16x8*)&w1[addr + h * 8] = ov;
    }
    __syncthreads();
  }
}

// ---------------------------------------------------------------------------
// Batched power-doubling GEMM: Out[z] = P * X_z  (fp32, 64x64 tile, 4x4 micro)
// X_z read via its transpose (stack of A^T entries); emits Out, Out^T and
// bf16(Out). One launch per doubling level: A^{batch+z+1} = A^{batch} * A^{z+1}.
// ---------------------------------------------------------------------------
__global__ __launch_bounds__(256) void gemm_pow(
    const float* __restrict__ P, const float* __restrict__ XTb,
    float* __restrict__ OutS, float* __restrict__ OutST,
    unsigned short* __restrict__ OutSb) {
  __shared__ float a_lds[64][40];
  __shared__ float b_lds[64][40];
  const size_t zo = (size_t)blockIdx.z << 16;  // * 65536
  const float* XT = XTb + zo;
  const int tid = threadIdx.x;
  const int tm = tid >> 4, tn = tid & 15;
  const int m0 = blockIdx.x * 64, n0 = blockIdx.y * 64;
  float acc[4][4];
#pragma unroll
  for (int i = 0; i < 4; ++i)
#pragma unroll
    for (int j = 0; j < 4; ++j) acc[i][j] = 0.f;

  for (int kb = 0; kb < 256; kb += 32) {
    __syncthreads();
#pragma unroll
    for (int q = 0; q < 2; ++q) {
      const int slot = q * 256 + tid;
      const int row = slot >> 3, s4 = slot & 7;
      *(float4*)&a_lds[row][s4 * 4] = *(const float4*)&P[(size_t)(m0 + row) * 256 + kb + s4 * 4];
      *(float4*)&b_lds[row][s4 * 4] = *(const float4*)&XT[(size_t)(n0 + row) * 256 + kb + s4 * 4];
    }
    __syncthreads();
#pragma unroll
    for (int k4 = 0; k4 < 8; ++k4) {
      float4 a4[4], b4[4];
#pragma unroll
      for (int i = 0; i < 4; ++i) a4[i] = *(const float4*)&a_lds[tm * 4 + i][k4 * 4];
#pragma unroll
      for (int j = 0; j < 4; ++j) b4[j] = *(const float4*)&b_lds[tn * 4 + j][k4 * 4];
#pragma unroll
      for (int i = 0; i < 4; ++i)
#pragma unroll
        for (int j = 0; j < 4; ++j)
          acc[i][j] += a4[i].x * b4[j].x + a4[i].y * b4[j].y +
                       a4[i].z * b4[j].z + a4[i].w * b4[j].w;
    }
  }
  float* Out = OutS + zo;
  float* OutT = OutST + zo;
  unsigned short* Ob = OutSb + zo;
#pragma unroll
  for (int i = 0; i < 4; ++i) {
    const int m = m0 + tm * 4 + i;
    float4 v = make_float4(acc[i][0], acc[i][1], acc[i][2], acc[i][3]);
    *(float4*)&Out[(size_t)m * 256 + n0 + tn * 4] = v;
    *(ushort4*)&Ob[(size_t)m * 256 + n0 + tn * 4] =
        make_ushort4(f2bf(v.x), f2bf(v.y), f2bf(v.z), f2bf(v.w));
#pragma unroll
    for (int j = 0; j < 4; ++j)
      OutT[(size_t)(n0 + tn * 4 + j) * 256 + m] = acc[i][j];
  }
}

// ---------------------------------------------------------------------------
// Fused prep: A_W -> A^T (MstackT[0], aliases Cbuf) + bf16(A) -> Mstackb[0]
// (blocks 0..63), encoder t=0 (64..95), f2bf B_W/Wd1/Wd2 (96..255).
// ---------------------------------------------------------------------------
__global__ __launch_bounds__(256) void prep_kernel(
    const float* __restrict__ in, const float* __restrict__ We1,
    const float* __restrict__ be1, const float* __restrict__ We2,
    const float* __restrict__ be2, const float* __restrict__ A_W,
    const float* __restrict__ B_W, const float* __restrict__ Wd1,
    const float* __restrict__ Wd2, float* __restrict__ AT0,
    unsigned short* __restrict__ Ab0, float* __restrict__ z0,
    unsigned short* __restrict__ BWb, unsigned short* __restrict__ Wd1b,
    unsigned short* __restrict__ Wd2b) {
  __shared__ float sm[1056];
  const int tid = threadIdx.x;
  const int blk = blockIdx.x;
  if (blk < 64) {
    const int bx = (blk & 7) * 32, by = (blk >> 3) * 32;
    const int lx = tid & 31, ly = tid >> 5;
#pragma unroll
    for (int i = 0; i < 4; ++i) {
      const float v = A_W[(size_t)(by + ly + 8 * i) * 256 + bx + lx];
      sm[(ly + 8 * i) * 33 + lx] = v;
      Ab0[(size_t)(by + ly + 8 * i) * 256 + bx + lx] = f2bf(v);
    }
    __syncthreads();
#pragma unroll
    for (int i = 0; i < 4; ++i)
      AT0[(size_t)(bx + ly + 8 * i) * 256 + by + lx] = sm[lx * 33 + ly + 8 * i];
  } else if (blk < 96) {
    const int b = blk - 64, e = tid;
    float* xb = sm;
    float* h1 = sm + 256;
    xb[e] = in[(size_t)b * TLEN * INDIM + e];
    __syncthreads();
    float acc = be1[e];
    const float4* w = (const float4*)(We1 + (size_t)e * 256);
#pragma unroll 8
    for (int d4 = 0; d4 < 64; ++d4) {
      float4 wv = w[d4];
      acc += wv.x * xb[4 * d4] + wv.y * xb[4 * d4 + 1] + wv.z * xb[4 * d4 + 2] + wv.w * xb[4 * d4 + 3];
    }
    h1[e] = leakyf(acc);
    __syncthreads();
    float a2 = be2[e];
    w = (const float4*)(We2 + (size_t)e * 256);
#pragma unroll 8
    for (int d4 = 0; d4 < 64; ++d4) {
      float4 wv = w[d4];
      a2 += wv.x * h1[4 * d4] + wv.y * h1[4 * d4 + 1] + wv.z * h1[4 * d4 + 2] + wv.w * h1[4 * d4 + 3];
    }
    z0[(size_t)b * 256 + e] = leakyf(a2);
  } else {
    const float* src;
    unsigned short* dst;
    int i4;
    if (blk < 128)      { src = B_W; dst = BWb;  i4 = (blk - 96) * 256 + tid; }
    else if (blk < 192) { src = Wd1; dst = Wd1b; i4 = (blk - 128) * 256 + tid; }
    else                { src = Wd2; dst = Wd2b; i4 = (blk - 192) * 256 + tid; }
    float4 v = *(const float4*)&src[(size_t)i4 * 4];
    *(ushort4*)&dst[(size_t)i4 * 4] =
        make_ushort4(f2bf(v.x), f2bf(v.y), f2bf(v.z), f2bf(v.w));
  }
}

// ---------------------------------------------------------------------------
// extract u columns -> dense bf16 [65536][128]
// ---------------------------------------------------------------------------
__global__ __launch_bounds__(256) void extract_u(const float* __restrict__ in,
                                                 unsigned short* __restrict__ ubuf) {
  const int gid = blockIdx.x * 256 + threadIdx.x;
  const int row = gid >> 5;
  const int c = (gid & 31) * 4;
  float4 v = *(const float4*)&in[(size_t)row * INDIM + 256 + c];
  *(ushort4*)&ubuf[(size_t)row * 128 + c] =
      make_ushort4(f2bf(v.x), f2bf(v.y), f2bf(v.z), f2bf(v.w));
}

// ---------------------------------------------------------------------------
// Phase kernel v6: zero-init scan; A in registers; d written as BF16 to the
// w1 staging buffer (8 B/thread/step, separate from Cbuf). v5's in-place
// fp32 store tripled the kernel's HBM traffic (write-allocate RFO on Cbuf +
// 150MB WRITE) and serialized a 4MB/step HBM round-trip into the scan
// (258us, VALUBusy 39%). This restores R2's store pattern (159us, 68%).
// ---------------------------------------------------------------------------
__global__ __launch_bounds__(512, 2) void phase_kernel(
    const float* __restrict__ AW, const float* __restrict__ Cbuf,
    float* __restrict__ Lend, unsigned short* __restrict__ dout) {
  const int tid = threadIdx.x;
  const int w = tid >> 6;
  const int lane = tid & 63;
  const int dg = lane & 7;        // d-group: owns d in [dg*32, dg*32+32)
  const int le = lane >> 3;       // e-quad within wave's 32-e slice
  const int e0 = w * 32 + le * 4;
  const int d0 = dg * 32;
  const int rho0 = blockIdx.x << 3;
  const int k = rho0 >> 5;
  const int b = (rho0 & 31) + dg;
  const int rho = rho0 + dg;

  __shared__ __align__(16) float carry[2][8][292];

  float4 Ar[4][8];
#pragma unroll
  for (int i = 0; i < 4; ++i)
#pragma unroll
    for (int k4 = 0; k4 < 8; ++k4)
      Ar[i][k4] = *(const float4*)&AW[(size_t)(e0 + i) * 256 + d0 + k4 * 4];

  float4 cur = make_float4(0.f, 0.f, 0.f, 0.f);
  const int epad = e0 + ((e0 >> 5) << 2);
  *(float4*)&carry[0][dg][epad] = cur;
  __syncthreads();

  const float4* crow = (const float4*)(Cbuf + ((size_t)b * TLEN + (size_t)k * CHL) * 256 + e0);
  ushort4* wrow = (ushort4*)(dout + ((size_t)b * TLEN + (size_t)k * CHL) * 256 + e0);

  int buf = 0;
  for (int j = 0; j < CHL; ++j) {
    const float4 cj = *crow;
    crow += 64;
    float4 s[8];
#pragma unroll
    for (int r = 0; r < 8; ++r) s[r] = make_float4(0.f, 0.f, 0.f, 0.f);
#pragma unroll
    for (int k4 = 0; k4 < 8; ++k4) {
      const float4 a0 = Ar[0][k4], a1 = Ar[1][k4], a2 = Ar[2][k4], a3 = Ar[3][k4];
#pragma unroll
      for (int r = 0; r < 8; ++r) {
        const float4 cv = *(const float4*)&carry[buf][r][dg * 36 + k4 * 4];
        s[r].x += a0.x * cv.x + a0.y * cv.y + a0.z * cv.z + a0.w * cv.w;
        s[r].y += a1.x * cv.x + a1.y * cv.y + a1.z * cv.z + a1.w * cv.w;
        s[r].z += a2.x * cv.x + a2.y * cv.y + a2.z * cv.z + a2.w * cv.w;
        s[r].w += a3.x * cv.x + a3.y * cv.y + a3.z * cv.z + a3.w * cv.w;
      }
    }
    float4 nxt = make_float4(0.f, 0.f, 0.f, 0.f);
#pragma unroll
    for (int r = 0; r < 8; ++r) {
      red8(s[r]);
      if (dg == r) nxt = s[r];
    }
    cur = make_float4(nxt.x + cj.x, nxt.y + cj.y, nxt.z + cj.z, nxt.w + cj.w);
    buf ^= 1;
    *(float4*)&carry[buf][dg][epad] = cur;
    *wrow = make_ushort4(f2bf(cur.x), f2bf(cur.y), f2bf(cur.z), f2bf(cur.w));
    wrow += 64;
    __syncthreads();
  }
  *(float4*)&Lend[(size_t)rho * 256 + e0] = cur;
}

// ---------------------------------------------------------------------------
// Boundary recurrence: E[k+1] = P*E[k] + Lend[k], P = A^32 (Mstack[31]).
// Register-P, DPP reduce; emits chunk-entry carries in bf16 for gemm_corr.
// ---------------------------------------------------------------------------
__global__ __launch_bounds__(512, 2) void boundary_kernel(
    const float* __restrict__ P, const float* __restrict__ z0,
    const float* __restrict__ Lend, unsigned short* __restrict__ Eb) {
  const int tid = threadIdx.x;
  const int w = tid >> 6;
  const int lane = tid & 63;
  const int dg = lane & 7;
  const int le = lane >> 3;
  const int e0 = w * 32 + le * 4;
  const int d0 = dg * 32;
  const int b = blockIdx.x;

  __shared__ __align__(16) float Ec[292];

  float4 Pr[4][8];
#pragma unroll
  for (int i = 0; i < 4; ++i)
#pragma unroll
    for (int k4 = 0; k4 < 8; ++k4)
      Pr[i][k4] = *(const float4*)&P[(size_t)(e0 + i) * 256 + d0 + k4 * 4];

  float4 cur = *(const float4*)&z0[(size_t)b * 256 + e0];
  const int epad = e0 + ((e0 >> 5) << 2);
  if (dg == 0) *(float4*)&Ec[epad] = cur;
  __syncthreads();

  for (int k = 0; k < NCH; ++k) {
    const float4 lv = *(const float4*)&Lend[((size_t)k * BSZ + b) * 256 + e0];
    if (dg == 0)
      *(ushort4*)&Eb[((size_t)k * BSZ + b) * 256 + e0] =
          make_ushort4(f2bf(cur.x), f2bf(cur.y), f2bf(cur.z), f2bf(cur.w));

    float4 s = make_float4(0.f, 0.f, 0.f, 0.f);
#pragma unroll
    for (int k4 = 0; k4 < 8; ++k4) {
      const float4 cv = *(const float4*)&Ec[dg * 36 + k4 * 4];
      s.x += Pr[0][k4].x * cv.x + Pr[0][k4].y * cv.y + Pr[0][k4].z * cv.z + Pr[0][k4].w * cv.w;
      s.y += Pr[1][k4].x * cv.x + Pr[1][k4].y * cv.y + Pr[1][k4].z * cv.z + Pr[1][k4].w * cv.w;
      s.z += Pr[2][k4].x * cv.x + Pr[2][k4].y * cv.y + Pr[2][k4].z * cv.z + Pr[2][k4].w * cv.w;
      s.w += Pr[3][k4].x * cv.x + Pr[3][k4].y * cv.y + Pr[3][k4].z * cv.z + Pr[3][k4].w * cv.w;
    }
    red8(s);
    cur = make_float4(s.x + lv.x, s.y + lv.y, s.z + lv.z, s.w + lv.w);
    __syncthreads();
    if (dg == 0) *(float4*)&Ec[epad] = cur;
    __syncthreads();
  }
}

// ---------------------------------------------------------------------------
extern "C" void kernel_launch(void* const* d_in, const int* in_sizes, int n_in,
                              void* d_out, int out_size, void* d_ws, size_t ws_size,
                              hipStream_t stream) {
  const float* in  = (const float*)d_in[0];
  const float* We1 = (const float*)d_in[1];
  const float* be1 = (const float*)d_in[2];
  const float* We2 = (const float*)d_in[3];
  const float* be2 = (const float*)d_in[4];
  const float* A_W = (const float*)d_in[5];
  const float* A_b = (const float*)d_in[6];
  const float* B_W = (const float*)d_in[7];
  const float* B_b = (const float*)d_in[8];
  const float* Wd1 = (const float*)d_in[9];
  const float* bd1 = (const float*)d_in[10];
  const float* Wd2 = (const float*)d_in[11];
  const float* bd2 = (const float*)d_in[12];
  float* out = (float*)d_out;

  float* ws     = (float*)d_ws;
  float* Cbuf   = ws;                          // 16,777,216 f (c_t)
  float* Mstack = Cbuf + 16777216;             // 32 x 65,536 f (entry i = A^{i+1}; entry 0 unused)
  float* z0     = Mstack + 2097152;            // 8,192 f
  float* Lend   = z0 + 8192;                   // 524,288 f
  unsigned short* Mstackb = (unsigned short*)(Lend + 524288);  // 32 x 65,536 us
  unsigned short* Eb   = Mstackb + 2097152;    // 524,288 us
  unsigned short* BWb  = Eb + 524288;          // 32,768 us
  unsigned short* Wd1b = BWb + 32768;          // 65,536 us
  unsigned short* Wd2b = Wd1b + 65536;         // 65,536 us
  // A^T stack lives in Cbuf's first 8 MB: dead before gemm_mfma writes Cbuf.
  float* MstackT = Cbuf;

  // d_out staging: [0,16MB) ubuf bf16; [16MB,48MB) d->w1 bf16; final fp32 overwrites
  unsigned short* ubuf = (unsigned short*)d_out;            // 65536x128 bf16
  unsigned short* w1   = ubuf + 8388608;                    // 65536x256 bf16 (d, then w1 in place)
  unsigned short* w2   = (unsigned short*)Cbuf;             // bf16 (Cbuf dead after phase)

  prep_kernel<<<256, 256, 0, stream>>>(in, We1, be1, We2, be2, A_W, B_W, Wd1,
                                       Wd2, MstackT, Mstackb, z0, BWb, Wd1b, Wd2b);

  // A^1..A^32 by batched doubling: A^{batch+z+1} = A^{batch} * A^{z+1}
  gemm_pow<<<dim3(4, 4, 1),  256, 0, stream>>>(A_W,                 MstackT, Mstack + 1 * 65536,  MstackT + 1 * 65536,  Mstackb + 1 * 65536);
  gemm_pow<<<dim3(4, 4, 2),  256, 0, stream>>>(Mstack + 1 * 65536,  MstackT, Mstack + 2 * 65536,  MstackT + 2 * 65536,  Mstackb + 2 * 65536);
  gemm_pow<<<dim3(4, 4, 4),  256, 0, stream>>>(Mstack + 3 * 65536,  MstackT, Mstack + 4 * 65536,  MstackT + 4 * 65536,  Mstackb + 4 * 65536);
  gemm_pow<<<dim3(4, 4, 8),  256, 0, stream>>>(Mstack + 7 * 65536,  MstackT, Mstack + 8 * 65536,  MstackT + 8 * 65536,  Mstackb + 8 * 65536);
  gemm_pow<<<dim3(4, 4, 16), 256, 0, stream>>>(Mstack + 15 * 65536, MstackT, Mstack + 16 * 65536, MstackT + 16 * 65536, Mstackb + 16 * 65536);

  extract_u<<<8192, 256, 0, stream>>>(in, ubuf);

  // c_t = u @ B_W^T + B_b + A_b -> Cbuf (fp32; overwrites the A^T stack alias)
  gemm_mfma<<<dim3(512, 2), 256, 0, stream>>>(ubuf, ALEN, BWb, A_b, B_b, 0, 0, Cbuf);

  // zero-init scan: d -> w1 buffer (bf16), chunk sums -> Lend
  phase_kernel<<<256, 512, 0, stream>>>(A_W, Cbuf, Lend, w1);
  // chunk-entry carries E[k,b] -> Eb (bf16)
  boundary_kernel<<<32, 512, 0, stream>>>(Mstack + 31 * 65536, z0, Lend, Eb);
  // w1 = bf16(ileaky(A^{jj+1} E + d))  [MFMA; reads d from w1, overwrites]
  gemm_corr<<<dim3(16, 64), 256, 0, stream>>>(Eb, Mstackb, w1);

  // dec1: w2 = bf16(inv_leaky(w1 @ Wd1^T + bd1))
  gemm_mfma<<<dim3(512, 2), 256, 0, stream>>>(w1, D256, Wd1b, bd1, nullptr, 1, 1, w2);
  // dec2: y = w2 @ Wd2^T + bd2 -> d_out (fp32)
  gemm_mfma<<<dim3(512, 2), 256, 0, stream>>>(w2, D256, Wd2b, bd2, nullptr, 0, 0, out);
}

// Round 5
// 652.267 us; speedup vs baseline: 1.2986x; 1.2986x over previous
//
#include <hip/hip_runtime.h>

#define D256 256
#define ALEN 128
#define INDIM 512
#define BSZ 32
#define TLEN 2048
#define CHL 32     // chunk length
#define NCH 64     // number of chunks

typedef __attribute__((ext_vector_type(8))) short short8;  // 8 x bf16
typedef __attribute__((ext_vector_type(4))) float f32x4;
typedef __attribute__((ext_vector_type(8))) unsigned short u16x8;

__device__ __forceinline__ float leakyf(float x)  { return x < 0.f ? 0.01f * x : x; }
__device__ __forceinline__ float ileakyf(float x) { return x < 0.f ? x * 100.0f : x; }

__device__ __forceinline__ unsigned short f2bf(float f) {
  unsigned int x = __float_as_uint(f);
  unsigned int r = x + 0x7FFFu + ((x >> 16) & 1u);  // RNE
  return (unsigned short)(r >> 16);
}

__device__ __forceinline__ float bf2f(unsigned short u) {
  return __uint_as_float(((unsigned int)u) << 16);
}

__device__ __forceinline__ void gload16(const void* g, const void* l) {
  __builtin_amdgcn_global_load_lds(
      (const __attribute__((address_space(1))) unsigned int*)g,
      (__attribute__((address_space(3))) unsigned int*)l, 16, 0, 0);
}

// cross-lane adds for the 8-way d-group reduction (dg = lane & 7).
template <int CTRL>
__device__ __forceinline__ float dpp_addf(float x) {
  return x + __int_as_float(__builtin_amdgcn_update_dpp(
                 0, __float_as_int(x), CTRL, 0xF, 0xF, true));
}
__device__ __forceinline__ void red8(float4& s) {
  s.x = dpp_addf<0xB1>(s.x); s.y = dpp_addf<0xB1>(s.y);
  s.z = dpp_addf<0xB1>(s.z); s.w = dpp_addf<0xB1>(s.w);   // xor 1
  s.x = dpp_addf<0x4E>(s.x); s.y = dpp_addf<0x4E>(s.y);
  s.z = dpp_addf<0x4E>(s.z); s.w = dpp_addf<0x4E>(s.w);   // xor 2
  s.x = dpp_addf<0x141>(s.x); s.y = dpp_addf<0x141>(s.y);
  s.z = dpp_addf<0x141>(s.z); s.w = dpp_addf<0x141>(s.w); // half-mirror (xor4-equiv)
}

// ---------------------------------------------------------------------------
// bf16 MFMA GEMM (m97 structure): Out[m][n] = sum_k In[m][k]*W[n][k]
// (+bias1[n]+bias2[n], optional inv_leaky). 128x128 tile, BK=32, 4 waves.
// Coalesced LDS-bounced epilogue (4 passes of 32 rows, 16B vector stores).
// ---------------------------------------------------------------------------
__global__ __launch_bounds__(256) void gemm_mfma(
    const unsigned short* __restrict__ In, int K,
    const unsigned short* __restrict__ W,
    const float* __restrict__ bias1, const float* __restrict__ bias2,
    int ileaky_act, int out_bf16, void* __restrict__ Outp) {
  __shared__ char lds[16384];
  __shared__ float ldsF[32][132];
  const int tid = threadIdx.x;
  const int lane = tid & 63, w = tid >> 6;
  const int m0 = blockIdx.x * 128, n0 = blockIdx.y * 128;
  const int wm = (w & 1) * 64, wn = (w >> 1) * 64;
  const int quad = lane >> 4, l16 = lane & 15;

  f32x4 acc[4][4];
#pragma unroll
  for (int i = 0; i < 4; ++i)
#pragma unroll
    for (int j = 0; j < 4; ++j) acc[i][j] = {0.f, 0.f, 0.f, 0.f};

  for (int kb = 0; kb < K; kb += 32) {
    __syncthreads();
#pragma unroll
    for (int q = 0; q < 2; ++q) {
      const int id = (w * 2 + q) * 64 + lane;
      const int row = id >> 2, ch = id & 3;
      gload16(In + (size_t)(m0 + row) * K + kb + ch * 8,
              lds + (w * 2 + q) * 1024);
      gload16(W + (size_t)(n0 + row) * K + kb + ch * 8,
              lds + 8192 + (w * 2 + q) * 1024);
    }
    __syncthreads();

    short8 af[4], bf[4];
#pragma unroll
    for (int i = 0; i < 4; ++i) {
      af[i] = *(const short8*)(lds + ((wm + i * 16 + l16) * 64 + quad * 16));
      bf[i] = *(const short8*)(lds + 8192 + ((wn + i * 16 + l16) * 64 + quad * 16));
    }
#pragma unroll
    for (int i = 0; i < 4; ++i)
#pragma unroll
      for (int j = 0; j < 4; ++j)
        acc[i][j] = __builtin_amdgcn_mfma_f32_16x16x32_bf16(af[i], bf[j], acc[i][j], 0, 0, 0);
  }

  // -------- coalesced epilogue: 4 passes of 32 rows through ldsF --------
  const int lrow = tid >> 3, c0 = (tid & 7) * 16;
#pragma unroll
  for (int p = 0; p < 4; ++p) {
    if ((w & 1) == (p >> 1)) {
      const int ib = 2 * (p & 1);
#pragma unroll
      for (int ii = 0; ii < 2; ++ii)
#pragma unroll
        for (int j = 0; j < 4; ++j)
#pragma unroll
          for (int r = 0; r < 4; ++r)
            ldsF[ii * 16 + quad * 4 + r][wn + j * 16 + l16] = acc[ib + ii][j][r];
    }
    __syncthreads();
    const int m = m0 + p * 32 + lrow;
    const int nb = n0 + c0;
    float v[16];
#pragma unroll
    for (int k = 0; k < 4; ++k) {
      const float4 b1 = *(const float4*)&bias1[nb + 4 * k];
#pragma unroll
      for (int c = 0; c < 4; ++c) v[4 * k + c] = ldsF[lrow][c0 + 4 * k + c] + ((const float*)&b1)[c];
    }
    if (bias2) {
#pragma unroll
      for (int k = 0; k < 4; ++k) {
        const float4 b2 = *(const float4*)&bias2[nb + 4 * k];
#pragma unroll
        for (int c = 0; c < 4; ++c) v[4 * k + c] += ((const float*)&b2)[c];
      }
    }
    if (ileaky_act) {
#pragma unroll
      for (int c = 0; c < 16; ++c) v[c] = ileakyf(v[c]);
    }
    if (out_bf16) {
      unsigned short* op = (unsigned short*)Outp + (size_t)m * 256 + nb;
#pragma unroll
      for (int h = 0; h < 2; ++h) {
        u16x8 ov;
#pragma unroll
        for (int c = 0; c < 8; ++c) ov[c] = f2bf(v[h * 8 + c]);
        *(u16x8*)(op + h * 8) = ov;
      }
    } else {
      float* op = (float*)Outp + (size_t)m * 256 + nb;
#pragma unroll
      for (int k = 0; k < 4; ++k)
        *(float4*)(op + 4 * k) = make_float4(v[4 * k], v[4 * k + 1], v[4 * k + 2], v[4 * k + 3]);
    }
    __syncthreads();
  }
}

// ---------------------------------------------------------------------------
// Correction GEMM: w1[b, k*CHL+jj, e] = bf16(ileaky( sum_d E[(k,b),d]*A^{jj+1}[e,d]
//   + d[b, k*CHL+jj, e] )).  In = Eb [2048][256] bf16; W = Mstackb [8192][256]
//   bf16 (row n = jj*256+e holds A^{jj+1}[e][:]); d = bf16, stored by
//   phase_kernel in the SAME buffer w1 (read-then-overwrite per element by
//   the owning thread). Coalesced LDS-bounced epilogue.
// ---------------------------------------------------------------------------
__global__ __launch_bounds__(256) void gemm_corr(
    const unsigned short* __restrict__ Eb, const unsigned short* __restrict__ Mb,
    unsigned short* w1 /* aliased: d in, w1 out */) {
  __shared__ char lds[16384];
  __shared__ float ldsF[32][132];
  const int tid = threadIdx.x;
  const int lane = tid & 63, w = tid >> 6;
  const int m0 = blockIdx.x * 128, n0 = blockIdx.y * 128;
  const int wm = (w & 1) * 64, wn = (w >> 1) * 64;
  const int quad = lane >> 4, l16 = lane & 15;

  f32x4 acc[4][4];
#pragma unroll
  for (int i = 0; i < 4; ++i)
#pragma unroll
    for (int j = 0; j < 4; ++j) acc[i][j] = {0.f, 0.f, 0.f, 0.f};

  for (int kb = 0; kb < 256; kb += 32) {
    __syncthreads();
#pragma unroll
    for (int q = 0; q < 2; ++q) {
      const int id = (w * 2 + q) * 64 + lane;
      const int row = id >> 2, ch = id & 3;
      gload16(Eb + (size_t)(m0 + row) * 256 + kb + ch * 8,
              lds + (w * 2 + q) * 1024);
      gload16(Mb + (size_t)(n0 + row) * 256 + kb + ch * 8,
              lds + 8192 + (w * 2 + q) * 1024);
    }
    __syncthreads();

    short8 af[4], bf[4];
#pragma unroll
    for (int i = 0; i < 4; ++i) {
      af[i] = *(const short8*)(lds + ((wm + i * 16 + l16) * 64 + quad * 16));
      bf[i] = *(const short8*)(lds + 8192 + ((wn + i * 16 + l16) * 64 + quad * 16));
    }
#pragma unroll
    for (int i = 0; i < 4; ++i)
#pragma unroll
      for (int j = 0; j < 4; ++j)
        acc[i][j] = __builtin_amdgcn_mfma_f32_16x16x32_bf16(af[i], bf[j], acc[i][j], 0, 0, 0);
  }

  // -------- coalesced epilogue; d-read + w1-write at identical addrs -----
  const int lrow = tid >> 3, c0 = (tid & 7) * 16;
#pragma unroll
  for (int p = 0; p < 4; ++p) {
    if ((w & 1) == (p >> 1)) {
      const int ib = 2 * (p & 1);
#pragma unroll
      for (int ii = 0; ii < 2; ++ii)
#pragma unroll
        for (int j = 0; j < 4; ++j)
#pragma unroll
          for (int r = 0; r < 4; ++r)
            ldsF[ii * 16 + quad * 4 + r][wn + j * 16 + l16] = acc[ib + ii][j][r];
    }
    __syncthreads();
    const int m = m0 + p * 32 + lrow;
    const int kk = m >> 5, bb = m & 31;
    const int nb = n0 + c0;
    const int jj = nb >> 8, e = nb & 255;
    const size_t addr = ((size_t)bb * TLEN + (size_t)kk * CHL + jj) * 256 + e;
#pragma unroll
    for (int h = 0; h < 2; ++h) {
      const u16x8 dv = *(const u16x8*)&w1[addr + h * 8];
      u16x8 ov;
#pragma unroll
      for (int c = 0; c < 8; ++c) {
        float v = ldsF[lrow][c0 + h * 8 + c] + bf2f(dv[c]);
        ov[c] = f2bf(ileakyf(v));
      }
      *(u16x8*)&w1[addr + h * 8] = ov;
    }
    __syncthreads();
  }
}

// ---------------------------------------------------------------------------
// Batched power-doubling GEMM: Out[z] = P * X_z  (fp32, 64x64 tile, 4x4 micro)
// X_z read via its transpose (stack of A^T entries); emits Out, Out^T and
// bf16(Out). One launch per doubling level: A^{batch+z+1} = A^{batch} * A^{z+1}.
// ---------------------------------------------------------------------------
__global__ __launch_bounds__(256) void gemm_pow(
    const float* __restrict__ P, const float* __restrict__ XTb,
    float* __restrict__ OutS, float* __restrict__ OutST,
    unsigned short* __restrict__ OutSb) {
  __shared__ float a_lds[64][40];
  __shared__ float b_lds[64][40];
  const size_t zo = (size_t)blockIdx.z << 16;  // * 65536
  const float* XT = XTb + zo;
  const int tid = threadIdx.x;
  const int tm = tid >> 4, tn = tid & 15;
  const int m0 = blockIdx.x * 64, n0 = blockIdx.y * 64;
  float acc[4][4];
#pragma unroll
  for (int i = 0; i < 4; ++i)
#pragma unroll
    for (int j = 0; j < 4; ++j) acc[i][j] = 0.f;

  for (int kb = 0; kb < 256; kb += 32) {
    __syncthreads();
#pragma unroll
    for (int q = 0; q < 2; ++q) {
      const int slot = q * 256 + tid;
      const int row = slot >> 3, s4 = slot & 7;
      *(float4*)&a_lds[row][s4 * 4] = *(const float4*)&P[(size_t)(m0 + row) * 256 + kb + s4 * 4];
      *(float4*)&b_lds[row][s4 * 4] = *(const float4*)&XT[(size_t)(n0 + row) * 256 + kb + s4 * 4];
    }
    __syncthreads();
#pragma unroll
    for (int k4 = 0; k4 < 8; ++k4) {
      float4 a4[4], b4[4];
#pragma unroll
      for (int i = 0; i < 4; ++i) a4[i] = *(const float4*)&a_lds[tm * 4 + i][k4 * 4];
#pragma unroll
      for (int j = 0; j < 4; ++j) b4[j] = *(const float4*)&b_lds[tn * 4 + j][k4 * 4];
#pragma unroll
      for (int i = 0; i < 4; ++i)
#pragma unroll
        for (int j = 0; j < 4; ++j)
          acc[i][j] += a4[i].x * b4[j].x + a4[i].y * b4[j].y +
                       a4[i].z * b4[j].z + a4[i].w * b4[j].w;
    }
  }
  float* Out = OutS + zo;
  float* OutT = OutST + zo;
  unsigned short* Ob = OutSb + zo;
#pragma unroll
  for (int i = 0; i < 4; ++i) {
    const int m = m0 + tm * 4 + i;
    float4 v = make_float4(acc[i][0], acc[i][1], acc[i][2], acc[i][3]);
    *(float4*)&Out[(size_t)m * 256 + n0 + tn * 4] = v;
    *(ushort4*)&Ob[(size_t)m * 256 + n0 + tn * 4] =
        make_ushort4(f2bf(v.x), f2bf(v.y), f2bf(v.z), f2bf(v.w));
#pragma unroll
    for (int j = 0; j < 4; ++j)
      OutT[(size_t)(n0 + tn * 4 + j) * 256 + m] = acc[i][j];
  }
}

// ---------------------------------------------------------------------------
// Fused prep: A_W -> A^T (MstackT[0], aliases Cbuf) + bf16(A) -> Mstackb[0]
// (blocks 0..63), encoder t=0 (64..95), f2bf B_W/Wd1/Wd2 (96..255).
// ---------------------------------------------------------------------------
__global__ __launch_bounds__(256) void prep_kernel(
    const float* __restrict__ in, const float* __restrict__ We1,
    const float* __restrict__ be1, const float* __restrict__ We2,
    const float* __restrict__ be2, const float* __restrict__ A_W,
    const float* __restrict__ B_W, const float* __restrict__ Wd1,
    const float* __restrict__ Wd2, float* __restrict__ AT0,
    unsigned short* __restrict__ Ab0, float* __restrict__ z0,
    unsigned short* __restrict__ BWb, unsigned short* __restrict__ Wd1b,
    unsigned short* __restrict__ Wd2b) {
  __shared__ float sm[1056];
  const int tid = threadIdx.x;
  const int blk = blockIdx.x;
  if (blk < 64) {
    const int bx = (blk & 7) * 32, by = (blk >> 3) * 32;
    const int lx = tid & 31, ly = tid >> 5;
#pragma unroll
    for (int i = 0; i < 4; ++i) {
      const float v = A_W[(size_t)(by + ly + 8 * i) * 256 + bx + lx];
      sm[(ly + 8 * i) * 33 + lx] = v;
      Ab0[(size_t)(by + ly + 8 * i) * 256 + bx + lx] = f2bf(v);
    }
    __syncthreads();
#pragma unroll
    for (int i = 0; i < 4; ++i)
      AT0[(size_t)(bx + ly + 8 * i) * 256 + by + lx] = sm[lx * 33 + ly + 8 * i];
  } else if (blk < 96) {
    const int b = blk - 64, e = tid;
    float* xb = sm;
    float* h1 = sm + 256;
    xb[e] = in[(size_t)b * TLEN * INDIM + e];
    __syncthreads();
    float acc = be1[e];
    const float4* w = (const float4*)(We1 + (size_t)e * 256);
#pragma unroll 8
    for (int d4 = 0; d4 < 64; ++d4) {
      float4 wv = w[d4];
      acc += wv.x * xb[4 * d4] + wv.y * xb[4 * d4 + 1] + wv.z * xb[4 * d4 + 2] + wv.w * xb[4 * d4 + 3];
    }
    h1[e] = leakyf(acc);
    __syncthreads();
    float a2 = be2[e];
    w = (const float4*)(We2 + (size_t)e * 256);
#pragma unroll 8
    for (int d4 = 0; d4 < 64; ++d4) {
      float4 wv = w[d4];
      a2 += wv.x * h1[4 * d4] + wv.y * h1[4 * d4 + 1] + wv.z * h1[4 * d4 + 2] + wv.w * h1[4 * d4 + 3];
    }
    z0[(size_t)b * 256 + e] = leakyf(a2);
  } else {
    const float* src;
    unsigned short* dst;
    int i4;
    if (blk < 128)      { src = B_W; dst = BWb;  i4 = (blk - 96) * 256 + tid; }
    else if (blk < 192) { src = Wd1; dst = Wd1b; i4 = (blk - 128) * 256 + tid; }
    else                { src = Wd2; dst = Wd2b; i4 = (blk - 192) * 256 + tid; }
    float4 v = *(const float4*)&src[(size_t)i4 * 4];
    *(ushort4*)&dst[(size_t)i4 * 4] =
        make_ushort4(f2bf(v.x), f2bf(v.y), f2bf(v.z), f2bf(v.w));
  }
}

// ---------------------------------------------------------------------------
// extract u columns -> dense bf16 [65536][128]
// ---------------------------------------------------------------------------
__global__ __launch_bounds__(256) void extract_u(const float* __restrict__ in,
                                                 unsigned short* __restrict__ ubuf) {
  const int gid = blockIdx.x * 256 + threadIdx.x;
  const int row = gid >> 5;
  const int c = (gid & 31) * 4;
  float4 v = *(const float4*)&in[(size_t)row * INDIM + 256 + c];
  *(ushort4*)&ubuf[(size_t)row * 128 + c] =
      make_ushort4(f2bf(v.x), f2bf(v.y), f2bf(v.z), f2bf(v.w));
}

// ---------------------------------------------------------------------------
// Phase kernel v7 = R2's proven v4 inner loop (r-outer, single s accumulator
// — 158.7us, VALUBusy 68%, FETCH 35MB, no spill) + the v6 structure around
// it: zero-init scan, d stored as bf16 into the w1 buffer, Lend written.
// v5/v6's k4-outer nest (s[8]+a-copies live over the 128-reg A tile) caused
// scratch spill: FETCH 810MB, WRITE 214MB, 364us. Reverted.
// ---------------------------------------------------------------------------
__global__ __launch_bounds__(512, 2) void phase_kernel(
    const float* __restrict__ AW, const float* __restrict__ Cbuf,
    float* __restrict__ Lend, unsigned short* __restrict__ dout) {
  const int tid = threadIdx.x;
  const int w = tid >> 6;
  const int lane = tid & 63;
  const int dg = lane & 7;        // d-group: owns d in [dg*32, dg*32+32)
  const int le = lane >> 3;       // e-quad within wave's 32-e slice
  const int e0 = w * 32 + le * 4;
  const int d0 = dg * 32;
  const int rho0 = blockIdx.x << 3;
  const int k = rho0 >> 5;
  const int b = (rho0 & 31) + dg;
  const int rho = rho0 + dg;

  __shared__ __align__(16) float carry[2][8][292];

  float4 Ar[4][8];
#pragma unroll
  for (int i = 0; i < 4; ++i)
#pragma unroll
    for (int k4 = 0; k4 < 8; ++k4)
      Ar[i][k4] = *(const float4*)&AW[(size_t)(e0 + i) * 256 + d0 + k4 * 4];

  float4 cur = make_float4(0.f, 0.f, 0.f, 0.f);
  const int epad = e0 + ((e0 >> 5) << 2);   // = w*36 + le*4
  *(float4*)&carry[0][dg][epad] = cur;
  __syncthreads();

  const float4* crow = (const float4*)(Cbuf + ((size_t)b * TLEN + (size_t)k * CHL) * 256 + e0);
  ushort4* wrow = (ushort4*)(dout + ((size_t)b * TLEN + (size_t)k * CHL) * 256 + e0);

  int buf = 0;
  for (int j = 0; j < CHL; ++j) {
    const float4 cj = *crow;  // independent of carry: latency hides under FMAs
    crow += 64;
    float4 nxt = make_float4(0.f, 0.f, 0.f, 0.f);
#pragma unroll
    for (int r = 0; r < 8; ++r) {
      float4 s = make_float4(0.f, 0.f, 0.f, 0.f);
#pragma unroll
      for (int k4 = 0; k4 < 8; ++k4) {
        const float4 cv = *(const float4*)&carry[buf][r][dg * 36 + k4 * 4];
        s.x += Ar[0][k4].x * cv.x + Ar[0][k4].y * cv.y + Ar[0][k4].z * cv.z + Ar[0][k4].w * cv.w;
        s.y += Ar[1][k4].x * cv.x + Ar[1][k4].y * cv.y + Ar[1][k4].z * cv.z + Ar[1][k4].w * cv.w;
        s.z += Ar[2][k4].x * cv.x + Ar[2][k4].y * cv.y + Ar[2][k4].z * cv.z + Ar[2][k4].w * cv.w;
        s.w += Ar[3][k4].x * cv.x + Ar[3][k4].y * cv.y + Ar[3][k4].z * cv.z + Ar[3][k4].w * cv.w;
      }
      red8(s);                // all 8 dg lanes end with the full d-sum
      if (dg == r) nxt = s;   // stash the rho this thread owns
    }
    cur = make_float4(nxt.x + cj.x, nxt.y + cj.y, nxt.z + cj.z, nxt.w + cj.w);
    buf ^= 1;
    *(float4*)&carry[buf][dg][epad] = cur;
    *wrow = make_ushort4(f2bf(cur.x), f2bf(cur.y), f2bf(cur.z), f2bf(cur.w));
    wrow += 64;
    __syncthreads();
  }
  *(float4*)&Lend[(size_t)rho * 256 + e0] = cur;
}

// ---------------------------------------------------------------------------
// Boundary recurrence: E[k+1] = P*E[k] + Lend[k], P = A^32 (Mstack[31]).
// Register-P, DPP reduce; emits chunk-entry carries in bf16 for gemm_corr.
// ---------------------------------------------------------------------------
__global__ __launch_bounds__(512, 2) void boundary_kernel(
    const float* __restrict__ P, const float* __restrict__ z0,
    const float* __restrict__ Lend, unsigned short* __restrict__ Eb) {
  const int tid = threadIdx.x;
  const int w = tid >> 6;
  const int lane = tid & 63;
  const int dg = lane & 7;
  const int le = lane >> 3;
  const int e0 = w * 32 + le * 4;
  const int d0 = dg * 32;
  const int b = blockIdx.x;

  __shared__ __align__(16) float Ec[292];

  float4 Pr[4][8];
#pragma unroll
  for (int i = 0; i < 4; ++i)
#pragma unroll
    for (int k4 = 0; k4 < 8; ++k4)
      Pr[i][k4] = *(const float4*)&P[(size_t)(e0 + i) * 256 + d0 + k4 * 4];

  float4 cur = *(const float4*)&z0[(size_t)b * 256 + e0];
  const int epad = e0 + ((e0 >> 5) << 2);
  if (dg == 0) *(float4*)&Ec[epad] = cur;
  __syncthreads();

  for (int k = 0; k < NCH; ++k) {
    const float4 lv = *(const float4*)&Lend[((size_t)k * BSZ + b) * 256 + e0];
    if (dg == 0)
      *(ushort4*)&Eb[((size_t)k * BSZ + b) * 256 + e0] =
          make_ushort4(f2bf(cur.x), f2bf(cur.y), f2bf(cur.z), f2bf(cur.w));

    float4 s = make_float4(0.f, 0.f, 0.f, 0.f);
#pragma unroll
    for (int k4 = 0; k4 < 8; ++k4) {
      const float4 cv = *(const float4*)&Ec[dg * 36 + k4 * 4];
      s.x += Pr[0][k4].x * cv.x + Pr[0][k4].y * cv.y + Pr[0][k4].z * cv.z + Pr[0][k4].w * cv.w;
      s.y += Pr[1][k4].x * cv.x + Pr[1][k4].y * cv.y + Pr[1][k4].z * cv.z + Pr[1][k4].w * cv.w;
      s.z += Pr[2][k4].x * cv.x + Pr[2][k4].y * cv.y + Pr[2][k4].z * cv.z + Pr[2][k4].w * cv.w;
      s.w += Pr[3][k4].x * cv.x + Pr[3][k4].y * cv.y + Pr[3][k4].z * cv.z + Pr[3][k4].w * cv.w;
    }
    red8(s);
    cur = make_float4(s.x + lv.x, s.y + lv.y, s.z + lv.z, s.w + lv.w);
    __syncthreads();
    if (dg == 0) *(float4*)&Ec[epad] = cur;
    __syncthreads();
  }
}

// ---------------------------------------------------------------------------
extern "C" void kernel_launch(void* const* d_in, const int* in_sizes, int n_in,
                              void* d_out, int out_size, void* d_ws, size_t ws_size,
                              hipStream_t stream) {
  const float* in  = (const float*)d_in[0];
  const float* We1 = (const float*)d_in[1];
  const float* be1 = (const float*)d_in[2];
  const float* We2 = (const float*)d_in[3];
  const float* be2 = (const float*)d_in[4];
  const float* A_W = (const float*)d_in[5];
  const float* A_b = (const float*)d_in[6];
  const float* B_W = (const float*)d_in[7];
  const float* B_b = (const float*)d_in[8];
  const float* Wd1 = (const float*)d_in[9];
  const float* bd1 = (const float*)d_in[10];
  const float* Wd2 = (const float*)d_in[11];
  const float* bd2 = (const float*)d_in[12];
  float* out = (float*)d_out;

  float* ws     = (float*)d_ws;
  float* Cbuf   = ws;                          // 16,777,216 f (c_t)
  float* Mstack = Cbuf + 16777216;             // 32 x 65,536 f (entry i = A^{i+1}; entry 0 unused)
  float* z0     = Mstack + 2097152;            // 8,192 f
  float* Lend   = z0 + 8192;                   // 524,288 f
  unsigned short* Mstackb = (unsigned short*)(Lend + 524288);  // 32 x 65,536 us
  unsigned short* Eb   = Mstackb + 2097152;    // 524,288 us
  unsigned short* BWb  = Eb + 524288;          // 32,768 us
  unsigned short* Wd1b = BWb + 32768;          // 65,536 us
  unsigned short* Wd2b = Wd1b + 65536;         // 65,536 us
  // A^T stack lives in Cbuf's first 8 MB: dead before gemm_mfma writes Cbuf.
  float* MstackT = Cbuf;

  // d_out staging: [0,16MB) ubuf bf16; [16MB,48MB) d->w1 bf16; final fp32 overwrites
  unsigned short* ubuf = (unsigned short*)d_out;            // 65536x128 bf16
  unsigned short* w1   = ubuf + 8388608;                    // 65536x256 bf16 (d, then w1 in place)
  unsigned short* w2   = (unsigned short*)Cbuf;             // bf16 (Cbuf dead after phase)

  prep_kernel<<<256, 256, 0, stream>>>(in, We1, be1, We2, be2, A_W, B_W, Wd1,
                                       Wd2, MstackT, Mstackb, z0, BWb, Wd1b, Wd2b);

  // A^1..A^32 by batched doubling: A^{batch+z+1} = A^{batch} * A^{z+1}
  gemm_pow<<<dim3(4, 4, 1),  256, 0, stream>>>(A_W,                 MstackT, Mstack + 1 * 65536,  MstackT + 1 * 65536,  Mstackb + 1 * 65536);
  gemm_pow<<<dim3(4, 4, 2),  256, 0, stream>>>(Mstack + 1 * 65536,  MstackT, Mstack + 2 * 65536,  MstackT + 2 * 65536,  Mstackb + 2 * 65536);
  gemm_pow<<<dim3(4, 4, 4),  256, 0, stream>>>(Mstack + 3 * 65536,  MstackT, Mstack + 4 * 65536,  MstackT + 4 * 65536,  Mstackb + 4 * 65536);
  gemm_pow<<<dim3(4, 4, 8),  256, 0, stream>>>(Mstack + 7 * 65536,  MstackT, Mstack + 8 * 65536,  MstackT + 8 * 65536,  Mstackb + 8 * 65536);
  gemm_pow<<<dim3(4, 4, 16), 256, 0, stream>>>(Mstack + 15 * 65536, MstackT, Mstack + 16 * 65536, MstackT + 16 * 65536, Mstackb + 16 * 65536);

  extract_u<<<8192, 256, 0, stream>>>(in, ubuf);

  // c_t = u @ B_W^T + B_b + A_b -> Cbuf (fp32; overwrites the A^T stack alias)
  gemm_mfma<<<dim3(512, 2), 256, 0, stream>>>(ubuf, ALEN, BWb, A_b, B_b, 0, 0, Cbuf);

  // zero-init scan: d -> w1 buffer (bf16), chunk sums -> Lend
  phase_kernel<<<256, 512, 0, stream>>>(A_W, Cbuf, Lend, w1);
  // chunk-entry carries E[k,b] -> Eb (bf16)
  boundary_kernel<<<32, 512, 0, stream>>>(Mstack + 31 * 65536, z0, Lend, Eb);
  // w1 = bf16(ileaky(A^{jj+1} E + d))  [MFMA; reads d from w1, overwrites]
  gemm_corr<<<dim3(16, 64), 256, 0, stream>>>(Eb, Mstackb, w1);

  // dec1: w2 = bf16(inv_leaky(w1 @ Wd1^T + bd1))
  gemm_mfma<<<dim3(512, 2), 256, 0, stream>>>(w1, D256, Wd1b, bd1, nullptr, 1, 1, w2);
  // dec2: y = w2 @ Wd2^T + bd2 -> d_out (fp32)
  gemm_mfma<<<dim3(512, 2), 256, 0, stream>>>(w2, D256, Wd2b, bd2, nullptr, 0, 0, out);
}